// Round 1
// 411.697 us; speedup vs baseline: 1.0158x; 1.0158x over previous
//
#include <hip/hip_runtime.h>
#include <hip/hip_bf16.h>
#include <cstdint>
#include <cstddef>

// Problem constants
#define HW   512
#define HW2  1024
#define SZ   (512 * 512)
#define NPT  (34 * 34)   // 1156 warped 1024-res points per 16x16 output tile
#define K_PTS 5          // ceil(1156 / 256)
#define SRCW 36          // staged source window: 36x36 (covers base span [t0-2,t0+19] +/- ~8px disp)
#define NSRC (SRCW * SRCW)   // 1296
#define MARG 9           // window origin = tile_origin - MARG

// jax.image.resize bilinear upsample 512->1024 taps for output index i (0..1023)
struct UpTap { int i0, i1; float w0, w1; };

__device__ __forceinline__ UpTap up_tap(int i) {
  UpTap t;
  int k = i >> 1;
  if ((i & 1) == 0) {
    t.i0 = k - 1; t.i1 = k; t.w0 = 0.25f; t.w1 = 0.75f;
    if (k == 0) { t.i0 = 0; t.w0 = 0.0f; t.w1 = 1.0f; }
  } else {
    t.i0 = k; t.i1 = k + 1; t.w0 = 0.75f; t.w1 = 0.25f;
    if (k == HW - 1) { t.i1 = HW - 1; t.w0 = 1.0f; t.w1 = 0.0f; }
  }
  return t;
}

// Value of bilinear-upsampled (512->1024) plane at integer 1024-coords (yi, xi), in-range assumed.
__device__ __forceinline__ float up_at(const float* __restrict__ plane, int yi, int xi) {
  UpTap ty = up_tap(yi), tx = up_tap(xi);
  const float* r0 = plane + (size_t)ty.i0 * HW;
  const float* r1 = plane + (size_t)ty.i1 * HW;
  float v00 = r0[tx.i0], v01 = r0[tx.i1];
  float v10 = r1[tx.i0], v11 = r1[tx.i1];
  return ty.w0 * (tx.w0 * v00 + tx.w1 * v01) + ty.w1 * (tx.w0 * v10 + tx.w1 * v11);
}

// Separable decomposition of (warp-bilinear in 1024-space) o (2x upsample):
// a 3-tap stencil on the 512 grid. Base clamped to [0,509]; out-of-range
// corners get weight 0 (zero padding, mask pre-clamp).
__device__ __forceinline__ void axis_taps(float s, int& base, float& w0, float& w1, float& w2) {
  float f0 = floorf(s);
  int i0 = (int)f0;
  float fr = s - f0;
  int b = (i0 & 1) ? (i0 >> 1) : (i0 >> 1) - 1;
  b = b < 0 ? 0 : (b > (HW - 3) ? (HW - 3) : b);
  float w[3] = {0.0f, 0.0f, 0.0f};
  if ((unsigned)i0 < (unsigned)HW2) {
    UpTap t = up_tap(i0);
    w[t.i0 - b] += (1.0f - fr) * t.w0;
    w[t.i1 - b] += (1.0f - fr) * t.w1;
  }
  if ((unsigned)(i0 + 1) < (unsigned)HW2) {
    UpTap t = up_tap(i0 + 1);
    w[t.i0 - b] += fr * t.w0;
    w[t.i1 - b] += fr * t.w1;
  }
  base = b; w0 = w[0]; w1 = w[1]; w2 = w[2];
}

// -------------------- K0: copy src channels (0..15) straight to output --------------------
__global__ void copy_src_kernel(const float* __restrict__ x, float* __restrict__ out) {
  const size_t half = (size_t)16 * SZ;
  const size_t nvec = half / 4;                 // float4
  size_t i = (size_t)blockIdx.x * blockDim.x + threadIdx.x;
  if (i < 2 * nvec) {
    size_t b = i / nvec, j = i % nvec;
    const float4* s = (const float4*)(x + b * 2 * half);
    float4* d = (float4*)(out + b * 2 * half);
    d[j] = s[j];
  }
}

// Per-point separable 3x3 stencil. locoff >= 0: index into staged 36x36 LDS window.
// locoff < 0: rare fallback, ~locoff = global by*HW+bx offset (displacement > ~8px).
struct PtTaps {
  int   locoff;
  float wy0, wy1, wy2, wx0, wx1, wx2;
};

__device__ __forceinline__ void compute_taps(const float* __restrict__ fx,
                                             const float* __restrict__ fy,
                                             int gx0, int gy0, int xo, int yo, int tid,
                                             PtTaps (&pt)[K_PTS]) {
  #pragma unroll
  for (int i = 0; i < K_PTS; ++i) {
    int p = tid + i * 256;
    pt[i].locoff = 0;
    pt[i].wy0 = pt[i].wy1 = pt[i].wy2 = 0.0f;
    pt[i].wx0 = pt[i].wx1 = pt[i].wx2 = 0.0f;
    if (p < NPT) {
      int ry = p / 34, rx = p % 34;
      int yy = gy0 + ry, xx = gx0 + rx;
      if ((unsigned)yy < (unsigned)HW2 && (unsigned)xx < (unsigned)HW2) {
        float sx = (float)xx + 2.0f * up_at(fx, yy, xx);
        float sy = (float)yy + 2.0f * up_at(fy, yy, xx);
        int bx, by;
        axis_taps(sx, bx, pt[i].wx0, pt[i].wx1, pt[i].wx2);
        axis_taps(sy, by, pt[i].wy0, pt[i].wy1, pt[i].wy2);
        int rx_ = bx - xo, ry_ = by - yo;
        if ((unsigned)rx_ <= (unsigned)(SRCW - 3) && (unsigned)ry_ <= (unsigned)(SRCW - 3))
          pt[i].locoff = ry_ * SRCW + rx_;          // in staged window
        else
          pt[i].locoff = ~(by * HW + bx);           // fallback: global offset
      }
    }
  }
}

// Stage a channel pair's 36x36 source window into LDS (float2 interleaved).
// Coords clamped to the image; clamped slots are only ever read with weight 0
// or not at all (bases are pre-clamped to [0,509]).
__device__ __forceinline__ void stage_pair(const float* __restrict__ p0,
                                           const float* __restrict__ p1,
                                           float2* __restrict__ s_src,
                                           int xo, int yo, int tid) {
  #pragma unroll
  for (int i = 0; i < 6; ++i) {                   // 6*256 = 1536 >= 1296
    int p = tid + i * 256;
    if (p < NSRC) {
      int r = p / SRCW, c = p % SRCW;
      int gy = yo + r; gy = gy < 0 ? 0 : (gy > HW - 1 ? HW - 1 : gy);
      int gx = xo + c; gx = gx < 0 ? 0 : (gx > HW - 1 ? HW - 1 : gx);
      size_t o = (size_t)gy * HW + gx;
      s_src[p] = make_float2(p0[o], p1[o]);
    }
  }
}

__device__ __forceinline__ float eval3_global(const float* __restrict__ pl, int off, const PtTaps& t) {
  const float* p0 = pl + off;
  float r0 = t.wx0 * p0[0]        + t.wx1 * p0[1]          + t.wx2 * p0[2];
  float r1 = t.wx0 * p0[HW]       + t.wx1 * p0[HW + 1]     + t.wx2 * p0[HW + 2];
  float r2 = t.wx0 * p0[2 * HW]   + t.wx1 * p0[2 * HW + 1] + t.wx2 * p0[2 * HW + 2];
  return t.wy0 * r0 + t.wy1 * r1 + t.wy2 * r2;
}

// Evaluate all points of a channel pair from the staged LDS window into s_tile.
__device__ __forceinline__ void eval_round(const float2* __restrict__ s_src,
                                           float2* __restrict__ s_tile,
                                           const float* __restrict__ plane0,
                                           const float* __restrict__ plane1,
                                           const PtTaps (&pt)[K_PTS], int tid) {
  #pragma unroll
  for (int i = 0; i < K_PTS; ++i) {
    int p = tid + i * 256;
    if (p < NPT) {
      const PtTaps t = pt[i];
      float a0, a1;
      if (t.locoff >= 0) {
        const float2* s = s_src + t.locoff;
        float2 v00 = s[0],        v01 = s[1],            v02 = s[2];
        float2 v10 = s[SRCW],     v11 = s[SRCW + 1],     v12 = s[SRCW + 2];
        float2 v20 = s[2 * SRCW], v21 = s[2 * SRCW + 1], v22 = s[2 * SRCW + 2];
        float r00 = t.wx0 * v00.x + t.wx1 * v01.x + t.wx2 * v02.x;
        float r10 = t.wx0 * v10.x + t.wx1 * v11.x + t.wx2 * v12.x;
        float r20 = t.wx0 * v20.x + t.wx1 * v21.x + t.wx2 * v22.x;
        float r01 = t.wx0 * v00.y + t.wx1 * v01.y + t.wx2 * v02.y;
        float r11 = t.wx0 * v10.y + t.wx1 * v11.y + t.wx2 * v12.y;
        float r21 = t.wx0 * v20.y + t.wx1 * v21.y + t.wx2 * v22.y;
        a0 = t.wy0 * r00 + t.wy1 * r10 + t.wy2 * r20;
        a1 = t.wy0 * r01 + t.wy1 * r11 + t.wy2 * r21;
      } else {                                     // ~never taken (|disp| > ~8px)
        int off = ~t.locoff;
        a0 = eval3_global(plane0, off, t);
        a1 = eval3_global(plane1, off, t);
      }
      s_tile[p] = make_float2(a0, a1);
    }
  }
}

// -------------------- K1/K4: res_warp_img(tgt, res_field, rollback=1) --------------------
// Per block: 16x16 output tile. Channel pair per round; source window staged in LDS,
// 9-tap gathers served from LDS (latency fix); next round's staging overlaps phase 3.
__global__ void warp_img_kernel(const float* __restrict__ x,    // [B,32,512,512]
                                const float* __restrict__ res,  // [B,2,512,512]
                                float* __restrict__ out)        // [B,32,512,512]
{
  __shared__ float2 s_src[NSRC];   // 10368 B
  __shared__ float2 s_tile[NPT];   //  9248 B   (total 19.6 KB -> 8 blocks/CU by LDS)

  const int b = blockIdx.z;
  const int tx0 = blockIdx.x * 16, ty0 = blockIdx.y * 16;
  const int gx0 = tx0 * 2 - 1, gy0 = ty0 * 2 - 1;
  const int xo = tx0 - MARG, yo = ty0 - MARG;
  const int tid = threadIdx.x;

  const float* resx = res + (size_t)b * 2 * SZ;
  const float* resy = resx + SZ;
  const float* tgt  = x + ((size_t)b * 32 + 16) * SZ;

  // Issue staging loads for round 0 first so they fly under tap computation.
  stage_pair(tgt, tgt + SZ, s_src, xo, yo, tid);

  PtTaps pt[K_PTS];
  compute_taps(resx, resy, gx0, gy0, xo, yo, tid, pt);

  // Downsample stencil weights for this thread's output pixel
  const int ly = tid >> 4, lx = tid & 15;
  const int oy = ty0 + ly, ox = tx0 + lx;
  const float RW[4] = {0.25f, 0.75f, 0.75f, 0.25f};
  float wy[4], wx[4];
  float sumy = 0.f, sumx = 0.f;
  #pragma unroll
  for (int d = 0; d < 4; ++d) {
    int g = 2 * oy - 1 + d;
    wy[d] = ((unsigned)g < (unsigned)HW2) ? RW[d] : 0.0f; sumy += wy[d];
    g = 2 * ox - 1 + d;
    wx[d] = ((unsigned)g < (unsigned)HW2) ? RW[d] : 0.0f; sumx += wx[d];
  }
  const float inv = 1.0f / (sumy * sumx);

  __syncthreads();                                 // s_src round 0 ready

  for (int c = 0; c < 16; c += 2) {
    const float* plane0 = tgt + (size_t)c * SZ;
    eval_round(s_src, s_tile, plane0, plane0 + SZ, pt, tid);
    __syncthreads();                               // s_tile ready; s_src free

    if (c < 14)                                    // overlap next staging with phase 3
      stage_pair(plane0 + 2 * SZ, plane0 + 3 * SZ, s_src, xo, yo, tid);

    float acc0 = 0.0f, acc1 = 0.0f;
    #pragma unroll
    for (int dy = 0; dy < 4; ++dy) {
      float r0 = 0.0f, r1 = 0.0f;
      const int base = (2 * ly + dy) * 34 + 2 * lx;
      #pragma unroll
      for (int dx = 0; dx < 4; ++dx) {
        float2 v = s_tile[base + dx];
        r0 += wx[dx] * v.x;
        r1 += wx[dx] * v.y;
      }
      acc0 += wy[dy] * r0;
      acc1 += wy[dy] * r1;
    }
    size_t o = (((size_t)b * 32 + 16 + c) * HW + oy) * HW + ox;
    out[o] = acc0 * inv;
    out[o + SZ] = acc1 * inv;
    __syncthreads();                               // s_src(next) ready; s_tile free
  }
}

// -------------------- K2: 3x3 conv over 50-ch bundle -> 2-ch adj --------------------
__global__ void conv_kernel(const float* __restrict__ x,
                            const float* __restrict__ warped,  // = out, ch 16..31
                            const float* __restrict__ res,
                            const float* __restrict__ Wc,      // [2,50,3,3]
                            const float* __restrict__ bc,      // [2]
                            float* __restrict__ adj)           // [B,2,512,512]
{
  __shared__ float sw[900];
  const int tid = threadIdx.y * 16 + threadIdx.x;
  for (int i = tid; i < 900; i += 256) sw[i] = Wc[i];
  __syncthreads();

  const int b = blockIdx.z;
  const int oy = blockIdx.y * 16 + threadIdx.y;
  const int ox = blockIdx.x * 16 + threadIdx.x;

  float acc0 = bc[0];
  float acc1 = bc[1];

  for (int ic = 0; ic < 50; ++ic) {
    const float* w0 = &sw[ic * 9];
    const float* w1 = &sw[450 + ic * 9];
    const float* plane;
    if (ic < 32)      plane = x      + ((size_t)b * 32 + ic) * SZ;
    else if (ic < 48) plane = warped + ((size_t)b * 32 + 16 + (ic - 32)) * SZ;
    else              plane = res    + ((size_t)b * 2 + (ic - 48)) * SZ;
    #pragma unroll
    for (int ky = 0; ky < 3; ++ky) {
      int yy = oy + ky - 1;
      bool yok = (unsigned)yy < (unsigned)HW;
      #pragma unroll
      for (int kx = 0; kx < 3; ++kx) {
        int xx = ox + kx - 1;
        float v = 0.0f;
        if (yok && (unsigned)xx < (unsigned)HW)
          v = plane[(size_t)yy * HW + xx];
        acc0 += v * w0[ky * 3 + kx];
        acc1 += v * w1[ky * 3 + kx];
      }
    }
  }
  adj[((size_t)b * 2 + 0) * SZ + (size_t)oy * HW + ox] = acc0;
  adj[((size_t)b * 2 + 1) * SZ + (size_t)oy * HW + ox] = acc1;
}

// -------------------- K3: new_res = adj + downsample(warp(up(res), 2*up(adj))) --------------------
// (the reference's *2 on the warped field values and the *0.5 after downsample cancel exactly)
__global__ void new_res_kernel(const float* __restrict__ res,  // [B,2,512,512]
                               const float* __restrict__ adj,  // [B,2,512,512]
                               float* __restrict__ nres)       // [B,2,512,512]
{
  __shared__ float2 s_src[NSRC];
  __shared__ float2 s_tile[NPT];

  const int b = blockIdx.z;
  const int tx0 = blockIdx.x * 16, ty0 = blockIdx.y * 16;
  const int gx0 = tx0 * 2 - 1, gy0 = ty0 * 2 - 1;
  const int xo = tx0 - MARG, yo = ty0 - MARG;
  const int tid = threadIdx.x;

  const float* adjx = adj + (size_t)b * 2 * SZ;
  const float* adjy = adjx + SZ;
  const float* res0 = res + (size_t)b * 2 * SZ;
  const float* res1 = res0 + SZ;

  stage_pair(res0, res1, s_src, xo, yo, tid);

  PtTaps pt[K_PTS];
  compute_taps(adjx, adjy, gx0, gy0, xo, yo, tid, pt);

  const int ly = tid >> 4, lx = tid & 15;
  const int oy = ty0 + ly, ox = tx0 + lx;
  const float RW[4] = {0.25f, 0.75f, 0.75f, 0.25f};
  float wy[4], wx[4];
  float sumy = 0.f, sumx = 0.f;
  #pragma unroll
  for (int d = 0; d < 4; ++d) {
    int g = 2 * oy - 1 + d;
    wy[d] = ((unsigned)g < (unsigned)HW2) ? RW[d] : 0.0f; sumy += wy[d];
    g = 2 * ox - 1 + d;
    wx[d] = ((unsigned)g < (unsigned)HW2) ? RW[d] : 0.0f; sumx += wx[d];
  }
  const float inv = 1.0f / (sumy * sumx);

  __syncthreads();
  eval_round(s_src, s_tile, res0, res1, pt, tid);
  __syncthreads();

  float acc0 = 0.0f, acc1 = 0.0f;
  #pragma unroll
  for (int dy = 0; dy < 4; ++dy) {
    float r0 = 0.0f, r1 = 0.0f;
    const int base = (2 * ly + dy) * 34 + 2 * lx;
    #pragma unroll
    for (int dx = 0; dx < 4; ++dx) {
      float2 v = s_tile[base + dx];
      r0 += wx[dx] * v.x;
      r1 += wx[dx] * v.y;
    }
    acc0 += wy[dy] * r0;
    acc1 += wy[dy] * r1;
  }
  size_t o = ((size_t)b * 2) * SZ + (size_t)oy * HW + ox;
  nres[o]      = acc0 * inv + adjx[(size_t)oy * HW + ox];
  nres[o + SZ] = acc1 * inv + adjy[(size_t)oy * HW + ox];
}

extern "C" void kernel_launch(void* const* d_in, const int* in_sizes, int n_in,
                              void* d_out, int out_size, void* d_ws, size_t ws_size,
                              hipStream_t stream) {
  const float* x   = (const float*)d_in[0];  // [2,32,512,512] f32
  const float* res = (const float*)d_in[1];  // [2,2,512,512]  f32
  const float* Wc  = (const float*)d_in[2];  // [2,50,3,3]     f32
  const float* bc  = (const float*)d_in[3];  // [2]            f32
  float* out = (float*)d_out;                // [2,32,512,512] f32

  float* adj  = (float*)d_ws;                // [2,2,512,512]
  float* nres = adj + (size_t)2 * 2 * SZ;    // [2,2,512,512]

  // K0: src passthrough (out channels 0..15 per batch)
  {
    const size_t nvec = 2 * ((size_t)16 * SZ / 4);
    copy_src_kernel<<<dim3((unsigned)((nvec + 255) / 256)), dim3(256), 0, stream>>>(x, out);
  }

  dim3 tile_grid(32, 32, 2);

  // K1: warped_tgt (stage A) -> out channels 16..31 (fp32 staging for conv)
  warp_img_kernel<<<tile_grid, dim3(256), 0, stream>>>(x, res, out);

  // K2: conv3x3 over [x(0..31) | out(16..31) | res] -> adj
  conv_kernel<<<tile_grid, dim3(16, 16), 0, stream>>>(x, out, res, Wc, bc, adj);

  // K3: new_res
  new_res_kernel<<<tile_grid, dim3(256), 0, stream>>>(res, adj, nres);

  // K4: hindsight warp -> out channels 16..31 (overwrites staging)
  warp_img_kernel<<<tile_grid, dim3(256), 0, stream>>>(x, nres, out);
}